// Round 13
// baseline (560.726 us; speedup 1.0000x reference)
//
#include <hip/hip_runtime.h>
#include <cstdint>
#include <cstddef>

typedef unsigned short u16;
typedef short s16x8 __attribute__((ext_vector_type(8)));
typedef unsigned short u16x8 __attribute__((ext_vector_type(8)));
typedef unsigned short u16x4 __attribute__((ext_vector_type(4)));
typedef float f32x4 __attribute__((ext_vector_type(4)));
typedef unsigned int u32;
typedef unsigned int u32x2 __attribute__((ext_vector_type(2)));
typedef unsigned int u32x4 __attribute__((ext_vector_type(4)));

#define MFMA_BF16(a, b, c) __builtin_amdgcn_mfma_f32_16x16x32_bf16((a), (b), (c), 0, 0, 0)

__device__ __forceinline__ float b2f(u16 u) {
    union { unsigned int i; float f; } x;
    x.i = ((unsigned int)u) << 16;
    return x.f;
}
// round-half-up bf16 pack: 2 VALU instead of 5; <=1ulp diff vs RNE.
__device__ __forceinline__ u16 f2b(float f) {
    union { float f; unsigned int i; } x;
    x.f = f;
    return (u16)((x.i + 0x8000u) >> 16);
}
// v_exp_f32 computes 2^x (ISA §3)
__device__ __forceinline__ float exp2_hw(float x) {
    float r;
    asm volatile("v_exp_f32 %0, %1" : "=v"(r) : "v"(x));
    return r;
}
// pack 2 f32 -> 2 bf16 in one VALU op (no builtin on gfx950; T12 recipe)
__device__ __forceinline__ unsigned int cvt_pk_bf16(float lo, float hi) {
    unsigned int r;
    asm("v_cvt_pk_bf16_f32 %0, %1, %2" : "=v"(r) : "v"(lo), "v"(hi));
    return r;
}

// async global->LDS, 16B per lane. LDS dest must be wave-uniform base + lane*16.
__device__ __forceinline__ void gload_lds16(const u16* g, u16* l) {
    __builtin_amdgcn_global_load_lds((__attribute__((address_space(1))) void*)(g),
                                     (__attribute__((address_space(3))) void*)(l),
                                     16, 0, 0);
}

// ---------------------------------------------------------------------------
// Merged prep: 6 weight transposes (+f32->bf16) and x convert, ONE launch.
// Transpose stages the tile TRANSPOSED in LDS (t[c][r]) so the store phase
// emits u16x8 (16B) global stores (round-10).
// ---------------------------------------------------------------------------
__device__ __forceinline__ void transpose_tile(const float* __restrict__ in,
                                               u16* __restrict__ out,
                                               int R, int C, int bx, int by) {
    __shared__ u16 t[64][68];   // t[c][r] = bf16(in[tr+r][tc+c])
    const int tc = bx * 64, tr = by * 64;
    for (int i = 0; i < 4; i++) {
        int idx = threadIdx.x + i * 256;      // 0..1023
        int r = idx >> 4, c4 = (idx & 15) * 4;
        float4 v = *(const float4*)(in + (size_t)(tr + r) * C + tc + c4);
        t[c4 + 0][r] = f2b(v.x);
        t[c4 + 1][r] = f2b(v.y);
        t[c4 + 2][r] = f2b(v.z);
        t[c4 + 3][r] = f2b(v.w);
    }
    __syncthreads();
    // out row (tc+x), cols tr+y0..y0+7  <-  t[x][y0..y0+7] (contiguous LDS)
    for (int i = 0; i < 2; i++) {
        int idx = threadIdx.x + i * 256;      // 0..511
        int x = idx >> 3, y0 = (idx & 7) * 8;
        *(u16x8*)(out + (size_t)(tc + x) * R + tr + y0) =
            *(const u16x8*)(&t[x][y0]);
    }
}

__global__ __launch_bounds__(256)
void prep_all(const float* __restrict__ w_q, const float* __restrict__ w_k,
              const float* __restrict__ w_v, const float* __restrict__ w_o,
              const float* __restrict__ w1, const float* __restrict__ w2,
              const float* __restrict__ x,
              u16* __restrict__ wqkv_t, u16* __restrict__ wo_t,
              u16* __restrict__ w1_t, u16* __restrict__ w2_t,
              u16* __restrict__ x_bf) {
    const int id = blockIdx.x;
    if (id < 1024) {
        const int j = id >> 8, lid = id & 255;
        const float* in = (j == 0) ? w_q : (j == 1) ? w_k : (j == 2) ? w_v : w_o;
        u16* out = (j == 0) ? wqkv_t
                 : (j == 1) ? wqkv_t + 1024 * 1024
                 : (j == 2) ? wqkv_t + 2 * 1024 * 1024
                 : wo_t;
        transpose_tile(in, out, 1024, 1024, lid & 15, lid >> 4);
    } else if (id < 2048) {
        const int lid = id - 1024;
        transpose_tile(w1, w1_t, 1024, 4096, lid & 63, lid >> 6);
    } else if (id < 3072) {
        const int lid = id - 2048;
        transpose_tile(w2, w2_t, 4096, 1024, lid & 15, lid >> 4);
    } else {
        const int i = ((id - 3072) * 256 + threadIdx.x) * 8;
        float4 a = *(const float4*)(x + i);
        float4 b = *(const float4*)(x + i + 4);
        u16x8 o;
        o[0] = f2b(a.x); o[1] = f2b(a.y); o[2] = f2b(a.z); o[3] = f2b(a.w);
        o[4] = f2b(b.x); o[5] = f2b(b.y); o[6] = f2b(b.z); o[7] = f2b(b.w);
        *(u16x8*)(x_bf + i) = o;
    }
}

enum { EPI_PLAIN = 0, EPI_RELU = 1, EPI_QKV = 2 };
#define SC_QK 0.1803368801111204f  // 0.125 * log2(e)

// ---------------------------------------------------------------------------
// gemm_bt: 128x128-tile GEMM (m97 structure). All four GEMMs use this.
// T1 XCD-contiguous block swizzle (bijective; all grids nwg%8==0): each XCD
// gets a contiguous m-major run -> B-panels L2-resident, halving L3 traffic
// (m192/m193: +10% A/B-confirmed on this structure).
// PLAIN/RELU compute with SWAPPED operands (round-10): output frag holds 4
// consecutive n per reg -> packed u16x4 epilogue stores.
// (256^2 pipelined variant killed the MI355X container in rounds 3+4 —
// do not reintroduce without isolating the failure.)
// ---------------------------------------------------------------------------
template <int EPI>
__global__ __launch_bounds__(256, 3)
void gemm_bt(const u16* __restrict__ A, const u16* __restrict__ Bt,
             const float* __restrict__ bias0, const float* __restrict__ bias1,
             const float* __restrict__ bias2,
             u16* __restrict__ C0, u16* __restrict__ C1, u16* __restrict__ C2,
             int M, int N, int K) {
    __shared__ u16 As[128 * 64];
    __shared__ u16 Bs[128 * 64];
    const int tid = threadIdx.x;
    const int lane = tid & 63;
    const int wave = tid >> 6;
    const int qd = lane >> 4, cl = lane & 15;
    const int wr = (wave >> 1) * 64, wc = (wave & 1) * 64;

    // T1: XCD-bijective contiguous-chunk swizzle (nwg % 8 == 0 for all grids)
    const int gx = gridDim.x;
    const int nwg = gx * gridDim.y;
    const int bid = blockIdx.y * gx + blockIdx.x;
    const int sid = (bid & 7) * (nwg >> 3) + (bid >> 3);
    const int m0 = (sid % gx) * 128, n0 = (sid / gx) * 128;

    const u16* AgP[4];
    const u16* BgP[4];
    int dsto[4];
    for (int c = 0; c < 4; c++) {
        const int d = tid * 8 + c * 2048;
        const int row = d >> 6;
        const int sblk = ((d >> 3) & 7) ^ (row & 7);
        AgP[c] = A + (size_t)(m0 + row) * K + sblk * 8;
        BgP[c] = Bt + (size_t)(n0 + row) * K + sblk * 8;
        dsto[c] = d;
    }

    const f32x4 Z = {0.f, 0.f, 0.f, 0.f};
    f32x4 acc[4][4];
    for (int i = 0; i < 4; i++)
        for (int j = 0; j < 4; j++) acc[i][j] = Z;

    for (int k = 0; k < K; k += 64) {
        __syncthreads();
        for (int c = 0; c < 4; c++) {
            gload_lds16(AgP[c] + k, As + dsto[c]);
            gload_lds16(BgP[c] + k, Bs + dsto[c]);
        }
        __syncthreads();
        for (int kk = 0; kk < 2; kk++) {
            s16x8 af[4], bfr[4];
            for (int i = 0; i < 4; i++) {
                const int row = wr + i * 16 + cl;
                af[i] = *(const s16x8*)(As + row * 64 +
                                        (((kk << 2) | qd) ^ (row & 7)) * 8);
            }
            for (int j = 0; j < 4; j++) {
                const int row = wc + j * 16 + cl;
                bfr[j] = *(const s16x8*)(Bs + row * 64 +
                                         (((kk << 2) | qd) ^ (row & 7)) * 8);
            }
            for (int i = 0; i < 4; i++)
                for (int j = 0; j < 4; j++) {
                    if (EPI == EPI_QKV)
                        acc[i][j] = MFMA_BF16(af[i], bfr[j], acc[i][j]);
                    else
                        acc[i][j] = MFMA_BF16(bfr[j], af[i], acc[i][j]);
                }
        }
    }

    if (EPI == EPI_QKV) {
        // Original epilogue: lane holds C[m = .. + qd*4 + r][n = .. + cl].
        for (int j = 0; j < 4; j++) {
            const int col = n0 + wc + j * 16 + cl;
            const int t = col >> 10, nn = col & 1023;
            const float* bp = (t == 0) ? bias0 : ((t == 1) ? bias1 : bias2);
            const float bv = bp[nn];
            if (t == 2) {
                // V^T output: 4 consecutive s per lane -> one 8B store
                const int hh = nn >> 6, d = nn & 63;
                for (int i = 0; i < 4; i++) {
                    const int row0 = m0 + wr + i * 16 + qd * 4;
                    const int b = row0 >> 11, s = row0 & 2047;
                    const int bh = b * 16 + hh;
                    u16x4 pk;
                    for (int r = 0; r < 4; r++) pk[r] = f2b(acc[i][j][r] + bv);
                    *(u16x4*)(&C2[((size_t)bh * 64 + d) * 2048 + s]) = pk;
                }
            } else {
                const int hh = nn >> 6, d = nn & 63;
                for (int i = 0; i < 4; i++) {
                    for (int r = 0; r < 4; r++) {
                        const int row = m0 + wr + i * 16 + qd * 4 + r;
                        const float v = acc[i][j][r] + bv;
                        const int b = row >> 11, s = row & 2047;
                        const int bh = b * 16 + hh;
                        if (t == 0)
                            C0[((size_t)bh * 2048 + s) * 64 + d] = f2b(v * SC_QK);
                        else
                            C1[((size_t)bh * 2048 + s) * 64 + d] = f2b(v);
                    }
                }
            }
        }
    } else {
        // Swapped epilogue: lane holds C[m = wr+i*16+cl][n = wc+j*16+qd*4+r]
        // -> 4 consecutive n per reg group: u16x4 stores, float4 bias.
        for (int i = 0; i < 4; i++) {
            const int row = m0 + wr + i * 16 + cl;
            for (int j = 0; j < 4; j++) {
                const int cb = n0 + wc + j * 16 + qd * 4;
                const float4 bv4 = *(const float4*)(bias0 + cb);
                const float bs[4] = {bv4.x, bv4.y, bv4.z, bv4.w};
                u16x4 pk;
                for (int r = 0; r < 4; r++) {
                    float v = acc[i][j][r] + bs[r];
                    if (EPI == EPI_RELU) v = fmaxf(v, 0.f);
                    pk[r] = f2b(v);
                }
                *(u16x4*)(&C0[(size_t)row * N + cb]) = pk;
            }
        }
    }
}

// ---------------------------------------------------------------------------
// Flash attention (round-9 structure, 96-97 us measured): swapped-operand
// MFMA, in-register P via permlane (bank-conflict 0), 2x-unrolled kb loop
// (compile-time buffer index), setprio around MFMA clusters. Unchanged.
// Serves as the cross-run internal control: if it reads ~103 us again the
// container is ~7% slow and totals must be normalized before comparison.
// ---------------------------------------------------------------------------
__global__ __launch_bounds__(256)
void flash_attn(const u16* __restrict__ Q, const u16* __restrict__ K,
                const u16* __restrict__ Vt, u16* __restrict__ ctx) {
    __shared__ u16 Ks[2][64 * 64];   // swizzled K tile [key][d], double-buffered
    __shared__ u16 Vs[2][64 * 64];   // swizzled V^T tile [d][key], double-buffered
    const int tid = threadIdx.x, lane = tid & 63, wave = tid >> 6;
    const int qd = lane >> 4, cl = lane & 15;
    const int bh = blockIdx.x;
    const int s0 = blockIdx.y * 128 + wave * 32;

    const u16* Kb = K + (size_t)bh * 2048 * 64;
    const u16* Vb = Vt + (size_t)bh * 64 * 2048;

    const int e0 = tid, e1 = tid + 256;
    const int r0 = e0 >> 3, bb0 = (e0 & 7) ^ (r0 & 7);
    const int r1 = e1 >> 3, bb1 = (e1 & 7) ^ (r1 & 7);

    // prologue: stage tile 0 into buffer 0 (issue first, load Q under it)
    gload_lds16(Kb + (size_t)r0 * 64 + bb0 * 8, &Ks[0][e0 * 8]);
    gload_lds16(Kb + (size_t)r1 * 64 + bb1 * 8, &Ks[0][e1 * 8]);
    gload_lds16(Vb + (size_t)r0 * 2048 + bb0 * 8, &Vs[0][e0 * 8]);
    gload_lds16(Vb + (size_t)r1 * 2048 + bb1 * 8, &Vs[0][e1 * 8]);

    const u16* Qb = Q + ((size_t)bh * 2048 + s0) * 64;
    s16x8 qf[2][2];
    for (int m = 0; m < 2; m++) {
        qf[m][0] = *(const s16x8*)(Qb + (m * 16 + cl) * 64 + qd * 8);
        qf[m][1] = *(const s16x8*)(Qb + (m * 16 + cl) * 64 + 32 + qd * 8);
    }

    s16x8 onesf;  // bf16 1.0 in every slot: A-operand for l = 1 @ P
    for (int i = 0; i < 8; i++) onesf[i] = (short)0x3F80;

    const f32x4 Z = {0.f, 0.f, 0.f, 0.f};
    f32x4 o_acc[2][4], l_acc[2];
    for (int m = 0; m < 2; m++) {
        l_acc[m] = Z;
        for (int t = 0; t < 4; t++) o_acc[m][t] = Z;
    }

    __syncthreads();  // drains prologue stage (vmcnt 0): buffer 0 ready

    // one kb sub-iteration; CUR is compile-time -> LDS addrs are immediates
#define ATTN_ITER(CUR, KB, DO_STAGE)                                           \
    {                                                                          \
        if (DO_STAGE) {                                                        \
            const int kn = (KB) + 1;                                           \
            gload_lds16(Kb + (size_t)(kn * 64 + r0) * 64 + bb0 * 8,            \
                        &Ks[(CUR) ^ 1][e0 * 8]);                               \
            gload_lds16(Kb + (size_t)(kn * 64 + r1) * 64 + bb1 * 8,            \
                        &Ks[(CUR) ^ 1][e1 * 8]);                               \
            gload_lds16(Vb + (size_t)r0 * 2048 + kn * 64 + bb0 * 8,            \
                        &Vs[(CUR) ^ 1][e0 * 8]);                               \
            gload_lds16(Vb + (size_t)r1 * 2048 + kn * 64 + bb1 * 8,            \
                        &Vs[(CUR) ^ 1][e1 * 8]);                               \
        }                                                                      \
        const u16* ks = Ks[CUR];                                               \
        const u16* vs = Vs[CUR];                                               \
        f32x4 sacc[2][4];                                                      \
        for (int m = 0; m < 2; m++)                                            \
            for (int t = 0; t < 4; t++) sacc[m][t] = Z;                        \
        __builtin_amdgcn_s_setprio(1);                                         \
        for (int t = 0; t < 4; t++) {                                          \
            const int row = t * 16 + cl;                                       \
            s16x8 kf0 = *(const s16x8*)(ks + row * 64 + (qd ^ (row & 7)) * 8); \
            s16x8 kf1 = *(const s16x8*)(ks + row * 64 +                        \
                                        ((qd + 4) ^ (row & 7)) * 8);           \
            for (int m = 0; m < 2; m++) {                                      \
                sacc[m][t] = MFMA_BF16(kf0, qf[m][0], sacc[m][t]);             \
                sacc[m][t] = MFMA_BF16(kf1, qf[m][1], sacc[m][t]);             \
            }                                                                  \
        }                                                                      \
        __builtin_amdgcn_s_setprio(0);                                         \
        u32x2 w[2][4];                                                         \
        for (int m = 0; m < 2; m++)                                            \
            for (int t = 0; t < 4; t++) {                                      \
                const float p0 = exp2_hw(sacc[m][t][0]);                       \
                const float p1 = exp2_hw(sacc[m][t][1]);                       \
                const float p2 = exp2_hw(sacc[m][t][2]);                       \
                const float p3 = exp2_hw(sacc[m][t][3]);                       \
                w[m][t][0] = cvt_pk_bf16(p0, p1);                              \
                w[m][t][1] = cvt_pk_bf16(p2, p3);                              \
            }                                                                  \
        __builtin_amdgcn_s_setprio(1);                                         \
        for (int kk = 0; kk < 2; kk++) {                                       \
            s16x8 vf[4];                                                       \
            for (int t = 0; t < 4; t++) {                                      \
                const int row = t * 16 + cl;                                   \
                vf[t] = *(const s16x8*)(vs + row * 64 +                        \
                                        ((kk * 4 + qd) ^ (row & 7)) * 8);      \
            }                                                                  \
            for (int m = 0; m < 2; m++) {                                      \
                union { u32x4 u; s16x8 s; } pfu;                               \
                for (int c = 0; c < 2; c++) {                                  \
                    u32 a = w[m][2 * kk][c];                                   \
                    u32 b = w[m][2 * kk + 1][c];                               \
                    asm("v_permlane32_swap_b32 %0, %1" : "+v"(a), "+v"(b));    \
                    asm("v_permlane16_swap_b32 %0, %1" : "+v"(a), "+v"(b));    \
                    pfu.u[c] = a;                                              \
                    pfu.u[2 + c] = b;                                          \
                }                                                              \
                const s16x8 pf = pfu.s;                                        \
                for (int t = 0; t < 4; t++)                                    \
                    o_acc[m][t] = MFMA_BF16(vf[t], pf, o_acc[m][t]);           \
                l_acc[m] = MFMA_BF16(onesf, pf, l_acc[m]);                     \
            }                                                                  \
        }                                                                      \
        __builtin_amdgcn_s_setprio(0);                                         \
        __syncthreads();                                                       \
    }

    for (int j = 0; j < 16; j++) {
        ATTN_ITER(0, 2 * j, true);          // kb even: stage 2j+1 into buf 1
        ATTN_ITER(1, 2 * j + 1, (j < 15));  // kb odd: stage 2j+2 into buf 0
    }
#undef ATTN_ITER

    // final: o_acc[m][t][r] = O[q = m*16+cl][d = t*16 + qd*4 + r]
    // -> 4 consecutive d per reg group: packed u16x4 stores, l from reg 0.
    const int b = bh >> 4, hh = bh & 15;
    for (int m = 0; m < 2; m++) {
        const float inv = 1.f / l_acc[m][0];
        const int s = s0 + m * 16 + cl;
        u16* cp = ctx + ((size_t)(b * 2048 + s)) * 1024 + hh * 64 + qd * 4;
        for (int t = 0; t < 4; t++) {
            u16x4 pk;
            for (int r = 0; r < 4; r++) pk[r] = f2b(o_acc[m][t][r] * inv);
            *(u16x4*)(cp + t * 16) = pk;
        }
    }
}

// ---------------------------------------------------------------------------
// Residual + LayerNorm: O = LN(X + Y) * g + b.  1 wave per 1024-wide row.
// MODE 0: X f32, Y bf16, O bf16 (in-place over Y allowed; row-local)
// MODE 1: X bf16, Y bf16, O f32
// ---------------------------------------------------------------------------
template <int MODE>
__global__ __launch_bounds__(256)
void ln_res(const void* __restrict__ Xv, const u16* __restrict__ Y,
            const float* __restrict__ G, const float* __restrict__ Bp,
            void* __restrict__ Ov) {
    const int row = blockIdx.x * 4 + (threadIdx.x >> 6);
    const int lane = threadIdx.x & 63;
    const int off = lane * 16;
    float v[16];
    float s = 0.f, s2 = 0.f;
    const u16* y = Y + (size_t)row * 1024 + off;
    if (MODE == 0) {
        const float* X = (const float*)Xv + (size_t)row * 1024 + off;
        for (int i = 0; i < 2; i++) {
            float4 xa = *(const float4*)(X + i * 8);
            float4 xb = *(const float4*)(X + i * 8 + 4);
            u16x8 yv = *(const u16x8*)(y + i * 8);
            float xs[8] = {xa.x, xa.y, xa.z, xa.w, xb.x, xb.y, xb.z, xb.w};
            for (int j = 0; j < 8; j++) {
                const float t = xs[j] + b2f(yv[j]);
                v[i * 8 + j] = t;
                s += t;
                s2 += t * t;
            }
        }
    } else {
        const u16* X = (const u16*)Xv + (size_t)row * 1024 + off;
        for (int i = 0; i < 2; i++) {
            u16x8 xv = *(const u16x8*)(X + i * 8);
            u16x8 yv = *(const u16x8*)(y + i * 8);
            for (int j = 0; j < 8; j++) {
                const float t = b2f(xv[j]) + b2f(yv[j]);
                v[i * 8 + j] = t;
                s += t;
                s2 += t * t;
            }
        }
    }
    for (int o = 32; o >= 1; o >>= 1) {
        s += __shfl_xor(s, o, 64);
        s2 += __shfl_xor(s2, o, 64);
    }
    const float mu = s * (1.f / 1024.f);
    const float var = s2 * (1.f / 1024.f) - mu * mu;
    const float rs = rsqrtf(var + 1e-5f);
    const float* g = G + off;
    const float* bp = Bp + off;
    for (int i = 0; i < 2; i++) {
        float4 ga = *(const float4*)(g + i * 8);
        float4 gb = *(const float4*)(g + i * 8 + 4);
        float4 ba = *(const float4*)(bp + i * 8);
        float4 bb = *(const float4*)(bp + i * 8 + 4);
        float gs[8] = {ga.x, ga.y, ga.z, ga.w, gb.x, gb.y, gb.z, gb.w};
        float bs[8] = {ba.x, ba.y, ba.z, ba.w, bb.x, bb.y, bb.z, bb.w};
        if (MODE == 0) {
            u16* o = (u16*)Ov + (size_t)row * 1024 + off;
            u16x8 ov;
            for (int j = 0; j < 8; j++)
                ov[j] = f2b((v[i * 8 + j] - mu) * rs * gs[j] + bs[j]);
            *(u16x8*)(o + i * 8) = ov;
        } else {
            float* o = (float*)Ov + (size_t)row * 1024 + off;
            float4 o0, o1;
            o0.x = (v[i * 8 + 0] - mu) * rs * gs[0] + bs[0];
            o0.y = (v[i * 8 + 1] - mu) * rs * gs[1] + bs[1];
            o0.z = (v[i * 8 + 2] - mu) * rs * gs[2] + bs[2];
            o0.w = (v[i * 8 + 3] - mu) * rs * gs[3] + bs[3];
            o1.x = (v[i * 8 + 4] - mu) * rs * gs[4] + bs[4];
            o1.y = (v[i * 8 + 5] - mu) * rs * gs[5] + bs[5];
            o1.z = (v[i * 8 + 6] - mu) * rs * gs[6] + bs[6];
            o1.w = (v[i * 8 + 7] - mu) * rs * gs[7] + bs[7];
            *(float4*)(o + i * 8) = o0;
            *(float4*)(o + i * 8 + 4) = o1;
        }
    }
}

// ---------------------------------------------------------------------------
extern "C" void kernel_launch(void* const* d_in, const int* in_sizes, int n_in,
                              void* d_out, int out_size, void* d_ws, size_t ws_size,
                              hipStream_t stream) {
    const float* x    = (const float*)d_in[0];
    const float* w_q  = (const float*)d_in[1];
    const float* b_q  = (const float*)d_in[2];
    const float* w_k  = (const float*)d_in[3];
    const float* b_k  = (const float*)d_in[4];
    const float* w_v  = (const float*)d_in[5];
    const float* b_v  = (const float*)d_in[6];
    const float* w_o  = (const float*)d_in[7];
    const float* b_o  = (const float*)d_in[8];
    const float* ln1g = (const float*)d_in[9];
    const float* ln1b = (const float*)d_in[10];
    const float* w1   = (const float*)d_in[11];
    const float* b1   = (const float*)d_in[12];
    const float* w2   = (const float*)d_in[13];
    const float* b2   = (const float*)d_in[14];
    const float* ln2g = (const float*)d_in[15];
    const float* ln2b = (const float*)d_in[16];
    float* out = (float*)d_out;

    char* ws = (char*)d_ws;
    const size_t MB = 1024 * 1024;
    u16* wqkv_t = (u16*)(ws + 0);         // [3072][1024]   6 MB
    u16* wo_t   = (u16*)(ws + 6 * MB);    // [1024][1024]   2 MB
    u16* w1_t   = (u16*)(ws + 8 * MB);    // [4096][1024]   8 MB
    u16* w2_t   = (u16*)(ws + 16 * MB);   // [1024][4096]   8 MB
    u16* x_bf   = (u16*)(ws + 24 * MB);   // [8192][1024]   16 MB
    u16* Qs     = (u16*)(ws + 40 * MB);   // [64][2048][64] 16 MB
    u16* Kk     = (u16*)(ws + 56 * MB);   // [64][2048][64] 16 MB
    u16* Vt     = (u16*)(ws + 72 * MB);   // [64][64][2048] 16 MB
    u16* ctx    = (u16*)(ws + 88 * MB);   // [8192][1024]   16 MB
    u16* attn   = (u16*)(ws + 104 * MB);  // [8192][1024]   16 MB
    u16* h      = attn;                   // LN1 in-place over attn (row-local)
    u16* ffn1   = (u16*)(ws + 24 * MB);   // [8192][4096]   64 MB (reuses x_bf/Q/K/Vt)
    u16* ffn2   = (u16*)(ws + 88 * MB);   // [8192][1024]   16 MB (reuses ctx)

    // merged prep: all weight transposes + x convert in one launch
    prep_all<<<7168, 256, 0, stream>>>(w_q, w_k, w_v, w_o, w1, w2, x,
                                       wqkv_t, wo_t, w1_t, w2_t, x_bf);

    // fused QKV projection (Q pre-scaled for exp2-domain softmax)
    gemm_bt<EPI_QKV><<<dim3(64, 24), 256, 0, stream>>>(
        x_bf, wqkv_t, b_q, b_k, b_v, Qs, Kk, Vt, 8192, 3072, 1024);

    // attention (128 q-rows per block; bh on x for XCD L2 locality)
    flash_attn<<<dim3(64, 16), 256, 0, stream>>>(Qs, Kk, Vt, ctx);

    // output projection
    gemm_bt<EPI_PLAIN><<<dim3(64, 8), 256, 0, stream>>>(
        ctx, wo_t, b_o, nullptr, nullptr, attn, nullptr, nullptr, 8192, 1024, 1024);

    // h = LN(x + attn)  (f32 x residual, bf16 out, in-place over attn)
    ln_res<0><<<2048, 256, 0, stream>>>(x, attn, ln1g, ln1b, h);

    // FFN
    gemm_bt<EPI_RELU><<<dim3(64, 32), 256, 0, stream>>>(
        h, w1_t, b1, nullptr, nullptr, ffn1, nullptr, nullptr, 8192, 4096, 1024);
    gemm_bt<EPI_PLAIN><<<dim3(64, 8), 256, 0, stream>>>(
        ffn1, w2_t, b2, nullptr, nullptr, ffn2, nullptr, nullptr, 8192, 1024, 4096);

    // out = LN(h + ffn2) -> f32
    ln_res<1><<<2048, 256, 0, stream>>>(h, ffn2, ln2g, ln2b, out);

    (void)in_sizes; (void)n_in; (void)out_size; (void)ws_size;
}

// Round 14
// 458.411 us; speedup vs baseline: 1.2232x; 1.2232x over previous
//
#include <hip/hip_runtime.h>
#include <cstdint>
#include <cstddef>

typedef unsigned short u16;
typedef short s16x8 __attribute__((ext_vector_type(8)));
typedef unsigned short u16x8 __attribute__((ext_vector_type(8)));
typedef unsigned short u16x4 __attribute__((ext_vector_type(4)));
typedef float f32x4 __attribute__((ext_vector_type(4)));
typedef unsigned int u32;
typedef unsigned int u32x2 __attribute__((ext_vector_type(2)));
typedef unsigned int u32x4 __attribute__((ext_vector_type(4)));

#define MFMA_BF16(a, b, c) __builtin_amdgcn_mfma_f32_16x16x32_bf16((a), (b), (c), 0, 0, 0)

__device__ __forceinline__ float b2f(u16 u) {
    union { unsigned int i; float f; } x;
    x.i = ((unsigned int)u) << 16;
    return x.f;
}
// round-half-up bf16 pack: 2 VALU instead of 5; <=1ulp diff vs RNE.
__device__ __forceinline__ u16 f2b(float f) {
    union { float f; unsigned int i; } x;
    x.f = f;
    return (u16)((x.i + 0x8000u) >> 16);
}
// v_exp_f32 computes 2^x (ISA §3)
__device__ __forceinline__ float exp2_hw(float x) {
    float r;
    asm volatile("v_exp_f32 %0, %1" : "=v"(r) : "v"(x));
    return r;
}
// pack 2 f32 -> 2 bf16 in one VALU op (no builtin on gfx950; T12 recipe)
__device__ __forceinline__ unsigned int cvt_pk_bf16(float lo, float hi) {
    unsigned int r;
    asm("v_cvt_pk_bf16_f32 %0, %1, %2" : "=v"(r) : "v"(lo), "v"(hi));
    return r;
}

// async global->LDS, 16B per lane. LDS dest must be wave-uniform base + lane*16.
__device__ __forceinline__ void gload_lds16(const u16* g, u16* l) {
    __builtin_amdgcn_global_load_lds((__attribute__((address_space(1))) void*)(g),
                                     (__attribute__((address_space(3))) void*)(l),
                                     16, 0, 0);
}

// ---------------------------------------------------------------------------
// Merged prep: 6 weight transposes (+f32->bf16) and x convert, ONE launch.
// blocks [0,1024): w_q/w_k/w_v/w_o 1024x1024 transposes (256 blocks each)
// blocks [1024,2048): w1 (1024x4096);  [2048,3072): w2 (4096x1024)
// blocks [3072,7168): x f32->bf16 (2048 elems/block)
// ---------------------------------------------------------------------------
__device__ __forceinline__ void transpose_tile(const float* __restrict__ in,
                                               u16* __restrict__ out,
                                               int R, int C, int bx, int by) {
    __shared__ u16 t[64][68];
    const int tc = bx * 64, tr = by * 64;
    for (int i = 0; i < 16; i++) {
        int idx = threadIdx.x + i * 256;
        int r = idx >> 6, c = idx & 63;
        t[r][c] = f2b(in[(size_t)(tr + r) * C + tc + c]);
    }
    __syncthreads();
    for (int i = 0; i < 16; i++) {
        int idx = threadIdx.x + i * 256;
        int r = idx >> 6, c = idx & 63;
        out[(size_t)(tc + r) * R + tr + c] = t[c][r];
    }
}

__global__ __launch_bounds__(256)
void prep_all(const float* __restrict__ w_q, const float* __restrict__ w_k,
              const float* __restrict__ w_v, const float* __restrict__ w_o,
              const float* __restrict__ w1, const float* __restrict__ w2,
              const float* __restrict__ x,
              u16* __restrict__ wqkv_t, u16* __restrict__ wo_t,
              u16* __restrict__ w1_t, u16* __restrict__ w2_t,
              u16* __restrict__ x_bf) {
    const int id = blockIdx.x;
    if (id < 1024) {
        const int j = id >> 8, lid = id & 255;
        const float* in = (j == 0) ? w_q : (j == 1) ? w_k : (j == 2) ? w_v : w_o;
        u16* out = (j == 0) ? wqkv_t
                 : (j == 1) ? wqkv_t + 1024 * 1024
                 : (j == 2) ? wqkv_t + 2 * 1024 * 1024
                 : wo_t;
        transpose_tile(in, out, 1024, 1024, lid & 15, lid >> 4);
    } else if (id < 2048) {
        const int lid = id - 1024;
        transpose_tile(w1, w1_t, 1024, 4096, lid & 63, lid >> 6);
    } else if (id < 3072) {
        const int lid = id - 2048;
        transpose_tile(w2, w2_t, 4096, 1024, lid & 15, lid >> 4);
    } else {
        const int i = ((id - 3072) * 256 + threadIdx.x) * 8;
        float4 a = *(const float4*)(x + i);
        float4 b = *(const float4*)(x + i + 4);
        u16x8 o;
        o[0] = f2b(a.x); o[1] = f2b(a.y); o[2] = f2b(a.z); o[3] = f2b(a.w);
        o[4] = f2b(b.x); o[5] = f2b(b.y); o[6] = f2b(b.z); o[7] = f2b(b.w);
        *(u16x8*)(x_bf + i) = o;
    }
}

enum { EPI_PLAIN = 0, EPI_RELU = 1, EPI_QKV = 2 };
#define SC_QK 0.1803368801111204f  // 0.125 * log2(e)

// ---------------------------------------------------------------------------
// gemm_bt: 128x128-tile GEMM (m97 structure). All four GEMMs use this.
// NO explicit XCD swizzle (round-13 lesson): the default bid-round-robin
// dispatch already gives each XCD a 2D co-resident set (8 m-panels x 4
// n-panels, A 4-way + B 8-way shared, both L2-fit). A 1D contiguous-chunk
// swizzle destroyed A-sharing -> A re-fetch 15x, FETCH 246MB/dispatch,
// HBM 3.2 TB/s, +60us total. Do not reintroduce.
// (256^2 pipelined variant killed the MI355X container in rounds 3+4.)
// ---------------------------------------------------------------------------
template <int EPI>
__global__ __launch_bounds__(256, 3)
void gemm_bt(const u16* __restrict__ A, const u16* __restrict__ Bt,
             const float* __restrict__ bias0, const float* __restrict__ bias1,
             const float* __restrict__ bias2,
             u16* __restrict__ C0, u16* __restrict__ C1, u16* __restrict__ C2,
             int M, int N, int K) {
    __shared__ u16 As[128 * 64];
    __shared__ u16 Bs[128 * 64];
    const int tid = threadIdx.x;
    const int lane = tid & 63;
    const int wave = tid >> 6;
    const int qd = lane >> 4, cl = lane & 15;
    const int wr = (wave >> 1) * 64, wc = (wave & 1) * 64;
    const int m0 = blockIdx.x * 128, n0 = blockIdx.y * 128;

    const u16* AgP[4];
    const u16* BgP[4];
    int dsto[4];
    for (int c = 0; c < 4; c++) {
        const int d = tid * 8 + c * 2048;
        const int row = d >> 6;
        const int sblk = ((d >> 3) & 7) ^ (row & 7);
        AgP[c] = A + (size_t)(m0 + row) * K + sblk * 8;
        BgP[c] = Bt + (size_t)(n0 + row) * K + sblk * 8;
        dsto[c] = d;
    }

    const f32x4 Z = {0.f, 0.f, 0.f, 0.f};
    f32x4 acc[4][4];
    for (int i = 0; i < 4; i++)
        for (int j = 0; j < 4; j++) acc[i][j] = Z;

    for (int k = 0; k < K; k += 64) {
        __syncthreads();
        for (int c = 0; c < 4; c++) {
            gload_lds16(AgP[c] + k, As + dsto[c]);
            gload_lds16(BgP[c] + k, Bs + dsto[c]);
        }
        __syncthreads();
        for (int kk = 0; kk < 2; kk++) {
            s16x8 af[4], bfr[4];
            for (int i = 0; i < 4; i++) {
                const int row = wr + i * 16 + cl;
                af[i] = *(const s16x8*)(As + row * 64 +
                                        (((kk << 2) | qd) ^ (row & 7)) * 8);
            }
            for (int j = 0; j < 4; j++) {
                const int row = wc + j * 16 + cl;
                bfr[j] = *(const s16x8*)(Bs + row * 64 +
                                         (((kk << 2) | qd) ^ (row & 7)) * 8);
            }
            for (int i = 0; i < 4; i++)
                for (int j = 0; j < 4; j++)
                    acc[i][j] = MFMA_BF16(af[i], bfr[j], acc[i][j]);
        }
    }

    for (int j = 0; j < 4; j++) {
        const int col = n0 + wc + j * 16 + cl;
        float bv;
        if (EPI == EPI_QKV) {
            const int t = col >> 10, nn = col & 1023;
            const float* bp = (t == 0) ? bias0 : ((t == 1) ? bias1 : bias2);
            bv = bp[nn];
        } else {
            bv = bias0[col];
        }
        if (EPI == EPI_QKV && (col >> 10) == 2) {
            const int nn = col & 1023;
            const int hh = nn >> 6, d = nn & 63;
            for (int i = 0; i < 4; i++) {
                const int row0 = m0 + wr + i * 16 + qd * 4;
                const int b = row0 >> 11, s = row0 & 2047;
                const int bh = b * 16 + hh;
                u16x4 pk;
                for (int r = 0; r < 4; r++) pk[r] = f2b(acc[i][j][r] + bv);
                *(u16x4*)(&C2[((size_t)bh * 64 + d) * 2048 + s]) = pk;
            }
        } else {
            for (int i = 0; i < 4; i++) {
                for (int r = 0; r < 4; r++) {
                    const int row = m0 + wr + i * 16 + qd * 4 + r;
                    float v = acc[i][j][r] + bv;
                    if (EPI == EPI_RELU) v = fmaxf(v, 0.f);
                    if (EPI == EPI_QKV) {
                        const int t = col >> 10, nn = col & 1023;
                        const int hh = nn >> 6, d = nn & 63;
                        const int b = row >> 11, s = row & 2047;
                        const int bh = b * 16 + hh;
                        if (t == 0)
                            C0[((size_t)bh * 2048 + s) * 64 + d] = f2b(v * SC_QK);
                        else
                            C1[((size_t)bh * 2048 + s) * 64 + d] = f2b(v);
                    } else {
                        C0[(size_t)row * N + col] = f2b(v);
                    }
                }
            }
        }
    }
}

// ---------------------------------------------------------------------------
// Flash attention (round-9 structure, 97.2 us measured — session best):
// swapped-operand MFMA, in-register P via permlane (bank-conflict 0),
// 2x-unrolled kb loop (compile-time buffer index), setprio around MFMA.
// ---------------------------------------------------------------------------
__global__ __launch_bounds__(256)
void flash_attn(const u16* __restrict__ Q, const u16* __restrict__ K,
                const u16* __restrict__ Vt, u16* __restrict__ ctx) {
    __shared__ u16 Ks[2][64 * 64];   // swizzled K tile [key][d], double-buffered
    __shared__ u16 Vs[2][64 * 64];   // swizzled V^T tile [d][key], double-buffered
    const int tid = threadIdx.x, lane = tid & 63, wave = tid >> 6;
    const int qd = lane >> 4, cl = lane & 15;
    const int bh = blockIdx.x;
    const int s0 = blockIdx.y * 128 + wave * 32;

    const u16* Kb = K + (size_t)bh * 2048 * 64;
    const u16* Vb = Vt + (size_t)bh * 64 * 2048;

    const int e0 = tid, e1 = tid + 256;
    const int r0 = e0 >> 3, bb0 = (e0 & 7) ^ (r0 & 7);
    const int r1 = e1 >> 3, bb1 = (e1 & 7) ^ (r1 & 7);

    // prologue: stage tile 0 into buffer 0 (issue first, load Q under it)
    gload_lds16(Kb + (size_t)r0 * 64 + bb0 * 8, &Ks[0][e0 * 8]);
    gload_lds16(Kb + (size_t)r1 * 64 + bb1 * 8, &Ks[0][e1 * 8]);
    gload_lds16(Vb + (size_t)r0 * 2048 + bb0 * 8, &Vs[0][e0 * 8]);
    gload_lds16(Vb + (size_t)r1 * 2048 + bb1 * 8, &Vs[0][e1 * 8]);

    const u16* Qb = Q + ((size_t)bh * 2048 + s0) * 64;
    s16x8 qf[2][2];
    for (int m = 0; m < 2; m++) {
        qf[m][0] = *(const s16x8*)(Qb + (m * 16 + cl) * 64 + qd * 8);
        qf[m][1] = *(const s16x8*)(Qb + (m * 16 + cl) * 64 + 32 + qd * 8);
    }

    s16x8 onesf;  // bf16 1.0 in every slot: A-operand for l = 1 @ P
    for (int i = 0; i < 8; i++) onesf[i] = (short)0x3F80;

    const f32x4 Z = {0.f, 0.f, 0.f, 0.f};
    f32x4 o_acc[2][4], l_acc[2];
    for (int m = 0; m < 2; m++) {
        l_acc[m] = Z;
        for (int t = 0; t < 4; t++) o_acc[m][t] = Z;
    }

    __syncthreads();  // drains prologue stage (vmcnt 0): buffer 0 ready

    // one kb sub-iteration; CUR is compile-time -> LDS addrs are immediates
#define ATTN_ITER(CUR, KB, DO_STAGE)                                           \
    {                                                                          \
        if (DO_STAGE) {                                                        \
            const int kn = (KB) + 1;                                           \
            gload_lds16(Kb + (size_t)(kn * 64 + r0) * 64 + bb0 * 8,            \
                        &Ks[(CUR) ^ 1][e0 * 8]);                               \
            gload_lds16(Kb + (size_t)(kn * 64 + r1) * 64 + bb1 * 8,            \
                        &Ks[(CUR) ^ 1][e1 * 8]);                               \
            gload_lds16(Vb + (size_t)r0 * 2048 + kn * 64 + bb0 * 8,            \
                        &Vs[(CUR) ^ 1][e0 * 8]);                               \
            gload_lds16(Vb + (size_t)r1 * 2048 + kn * 64 + bb1 * 8,            \
                        &Vs[(CUR) ^ 1][e1 * 8]);                               \
        }                                                                      \
        const u16* ks = Ks[CUR];                                               \
        const u16* vs = Vs[CUR];                                               \
        f32x4 sacc[2][4];                                                      \
        for (int m = 0; m < 2; m++)                                            \
            for (int t = 0; t < 4; t++) sacc[m][t] = Z;                        \
        __builtin_amdgcn_s_setprio(1);                                         \
        for (int t = 0; t < 4; t++) {                                          \
            const int row = t * 16 + cl;                                       \
            s16x8 kf0 = *(const s16x8*)(ks + row * 64 + (qd ^ (row & 7)) * 8); \
            s16x8 kf1 = *(const s16x8*)(ks + row * 64 +                        \
                                        ((qd + 4) ^ (row & 7)) * 8);           \
            for (int m = 0; m < 2; m++) {                                      \
                sacc[m][t] = MFMA_BF16(kf0, qf[m][0], sacc[m][t]);             \
                sacc[m][t] = MFMA_BF16(kf1, qf[m][1], sacc[m][t]);             \
            }                                                                  \
        }                                                                      \
        __builtin_amdgcn_s_setprio(0);                                         \
        u32x2 w[2][4];                                                         \
        for (int m = 0; m < 2; m++)                                            \
            for (int t = 0; t < 4; t++) {                                      \
                const float p0 = exp2_hw(sacc[m][t][0]);                       \
                const float p1 = exp2_hw(sacc[m][t][1]);                       \
                const float p2 = exp2_hw(sacc[m][t][2]);                       \
                const float p3 = exp2_hw(sacc[m][t][3]);                       \
                w[m][t][0] = cvt_pk_bf16(p0, p1);                              \
                w[m][t][1] = cvt_pk_bf16(p2, p3);                              \
            }                                                                  \
        __builtin_amdgcn_s_setprio(1);                                         \
        for (int kk = 0; kk < 2; kk++) {                                       \
            s16x8 vf[4];                                                       \
            for (int t = 0; t < 4; t++) {                                      \
                const int row = t * 16 + cl;                                   \
                vf[t] = *(const s16x8*)(vs + row * 64 +                        \
                                        ((kk * 4 + qd) ^ (row & 7)) * 8);      \
            }                                                                  \
            for (int m = 0; m < 2; m++) {                                      \
                union { u32x4 u; s16x8 s; } pfu;                               \
                for (int c = 0; c < 2; c++) {                                  \
                    u32 a = w[m][2 * kk][c];                                   \
                    u32 b = w[m][2 * kk + 1][c];                               \
                    asm("v_permlane32_swap_b32 %0, %1" : "+v"(a), "+v"(b));    \
                    asm("v_permlane16_swap_b32 %0, %1" : "+v"(a), "+v"(b));    \
                    pfu.u[c] = a;                                              \
                    pfu.u[2 + c] = b;                                          \
                }                                                              \
                const s16x8 pf = pfu.s;                                        \
                for (int t = 0; t < 4; t++)                                    \
                    o_acc[m][t] = MFMA_BF16(vf[t], pf, o_acc[m][t]);           \
                l_acc[m] = MFMA_BF16(onesf, pf, l_acc[m]);                     \
            }                                                                  \
        }                                                                      \
        __builtin_amdgcn_s_setprio(0);                                         \
        __syncthreads();                                                       \
    }

    for (int j = 0; j < 16; j++) {
        ATTN_ITER(0, 2 * j, true);          // kb even: stage 2j+1 into buf 1
        ATTN_ITER(1, 2 * j + 1, (j < 15));  // kb odd: stage 2j+2 into buf 0
    }
#undef ATTN_ITER

    // final: o_acc[m][t][r] = O[q = m*16+cl][d = t*16 + qd*4 + r]
    // -> 4 consecutive d per reg group: packed u16x4 stores, l from reg 0.
    const int b = bh >> 4, hh = bh & 15;
    for (int m = 0; m < 2; m++) {
        const float inv = 1.f / l_acc[m][0];
        const int s = s0 + m * 16 + cl;
        u16* cp = ctx + ((size_t)(b * 2048 + s)) * 1024 + hh * 64 + qd * 4;
        for (int t = 0; t < 4; t++) {
            u16x4 pk;
            for (int r = 0; r < 4; r++) pk[r] = f2b(o_acc[m][t][r] * inv);
            *(u16x4*)(cp + t * 16) = pk;
        }
    }
}

// ---------------------------------------------------------------------------
// Residual + LayerNorm: O = LN(X + Y) * g + b.  1 wave per 1024-wide row.
// MODE 0: X f32, Y bf16, O bf16 (in-place over Y allowed; row-local)
// MODE 1: X bf16, Y bf16, O f32
// ---------------------------------------------------------------------------
template <int MODE>
__global__ __launch_bounds__(256)
void ln_res(const void* __restrict__ Xv, const u16* __restrict__ Y,
            const float* __restrict__ G, const float* __restrict__ Bp,
            void* __restrict__ Ov) {
    const int row = blockIdx.x * 4 + (threadIdx.x >> 6);
    const int lane = threadIdx.x & 63;
    const int off = lane * 16;
    float v[16];
    float s = 0.f, s2 = 0.f;
    const u16* y = Y + (size_t)row * 1024 + off;
    if (MODE == 0) {
        const float* X = (const float*)Xv + (size_t)row * 1024 + off;
        for (int i = 0; i < 2; i++) {
            float4 xa = *(const float4*)(X + i * 8);
            float4 xb = *(const float4*)(X + i * 8 + 4);
            u16x8 yv = *(const u16x8*)(y + i * 8);
            float xs[8] = {xa.x, xa.y, xa.z, xa.w, xb.x, xb.y, xb.z, xb.w};
            for (int j = 0; j < 8; j++) {
                const float t = xs[j] + b2f(yv[j]);
                v[i * 8 + j] = t;
                s += t;
                s2 += t * t;
            }
        }
    } else {
        const u16* X = (const u16*)Xv + (size_t)row * 1024 + off;
        for (int i = 0; i < 2; i++) {
            u16x8 xv = *(const u16x8*)(X + i * 8);
            u16x8 yv = *(const u16x8*)(y + i * 8);
            for (int j = 0; j < 8; j++) {
                const float t = b2f(xv[j]) + b2f(yv[j]);
                v[i * 8 + j] = t;
                s += t;
                s2 += t * t;
            }
        }
    }
    for (int o = 32; o >= 1; o >>= 1) {
        s += __shfl_xor(s, o, 64);
        s2 += __shfl_xor(s2, o, 64);
    }
    const float mu = s * (1.f / 1024.f);
    const float var = s2 * (1.f / 1024.f) - mu * mu;
    const float rs = rsqrtf(var + 1e-5f);
    const float* g = G + off;
    const float* bp = Bp + off;
    for (int i = 0; i < 2; i++) {
        float4 ga = *(const float4*)(g + i * 8);
        float4 gb = *(const float4*)(g + i * 8 + 4);
        float4 ba = *(const float4*)(bp + i * 8);
        float4 bb = *(const float4*)(bp + i * 8 + 4);
        float gs[8] = {ga.x, ga.y, ga.z, ga.w, gb.x, gb.y, gb.z, gb.w};
        float bs[8] = {ba.x, ba.y, ba.z, ba.w, bb.x, bb.y, bb.z, bb.w};
        if (MODE == 0) {
            u16* o = (u16*)Ov + (size_t)row * 1024 + off;
            u16x8 ov;
            for (int j = 0; j < 8; j++)
                ov[j] = f2b((v[i * 8 + j] - mu) * rs * gs[j] + bs[j]);
            *(u16x8*)(o + i * 8) = ov;
        } else {
            float* o = (float*)Ov + (size_t)row * 1024 + off;
            float4 o0, o1;
            o0.x = (v[i * 8 + 0] - mu) * rs * gs[0] + bs[0];
            o0.y = (v[i * 8 + 1] - mu) * rs * gs[1] + bs[1];
            o0.z = (v[i * 8 + 2] - mu) * rs * gs[2] + bs[2];
            o0.w = (v[i * 8 + 3] - mu) * rs * gs[3] + bs[3];
            o1.x = (v[i * 8 + 4] - mu) * rs * gs[4] + bs[4];
            o1.y = (v[i * 8 + 5] - mu) * rs * gs[5] + bs[5];
            o1.z = (v[i * 8 + 6] - mu) * rs * gs[6] + bs[6];
            o1.w = (v[i * 8 + 7] - mu) * rs * gs[7] + bs[7];
            *(float4*)(o + i * 8) = o0;
            *(float4*)(o + i * 8 + 4) = o1;
        }
    }
}

// ---------------------------------------------------------------------------
extern "C" void kernel_launch(void* const* d_in, const int* in_sizes, int n_in,
                              void* d_out, int out_size, void* d_ws, size_t ws_size,
                              hipStream_t stream) {
    const float* x    = (const float*)d_in[0];
    const float* w_q  = (const float*)d_in[1];
    const float* b_q  = (const float*)d_in[2];
    const float* w_k  = (const float*)d_in[3];
    const float* b_k  = (const float*)d_in[4];
    const float* w_v  = (const float*)d_in[5];
    const float* b_v  = (const float*)d_in[6];
    const float* w_o  = (const float*)d_in[7];
    const float* b_o  = (const float*)d_in[8];
    const float* ln1g = (const float*)d_in[9];
    const float* ln1b = (const float*)d_in[10];
    const float* w1   = (const float*)d_in[11];
    const float* b1   = (const float*)d_in[12];
    const float* w2   = (const float*)d_in[13];
    const float* b2   = (const float*)d_in[14];
    const float* ln2g = (const float*)d_in[15];
    const float* ln2b = (const float*)d_in[16];
    float* out = (float*)d_out;

    char* ws = (char*)d_ws;
    const size_t MB = 1024 * 1024;
    u16* wqkv_t = (u16*)(ws + 0);         // [3072][1024]   6 MB
    u16* wo_t   = (u16*)(ws + 6 * MB);    // [1024][1024]   2 MB
    u16* w1_t   = (u16*)(ws + 8 * MB);    // [4096][1024]   8 MB
    u16* w2_t   = (u16*)(ws + 16 * MB);   // [1024][4096]   8 MB
    u16* x_bf   = (u16*)(ws + 24 * MB);   // [8192][1024]   16 MB
    u16* Qs     = (u16*)(ws + 40 * MB);   // [64][2048][64] 16 MB
    u16* Kk     = (u16*)(ws + 56 * MB);   // [64][2048][64] 16 MB
    u16* Vt     = (u16*)(ws + 72 * MB);   // [64][64][2048] 16 MB
    u16* ctx    = (u16*)(ws + 88 * MB);   // [8192][1024]   16 MB
    u16* attn   = (u16*)(ws + 104 * MB);  // [8192][1024]   16 MB
    u16* h      = attn;                   // LN1 in-place over attn (row-local)
    u16* ffn1   = (u16*)(ws + 24 * MB);   // [8192][4096]   64 MB (reuses x_bf/Q/K/Vt)
    u16* ffn2   = (u16*)(ws + 88 * MB);   // [8192][1024]   16 MB (reuses ctx)

    // merged prep: all weight transposes + x convert in one launch
    prep_all<<<7168, 256, 0, stream>>>(w_q, w_k, w_v, w_o, w1, w2, x,
                                       wqkv_t, wo_t, w1_t, w2_t, x_bf);

    // fused QKV projection (Q pre-scaled for exp2-domain softmax)
    gemm_bt<EPI_QKV><<<dim3(64, 24), 256, 0, stream>>>(
        x_bf, wqkv_t, b_q, b_k, b_v, Qs, Kk, Vt, 8192, 3072, 1024);

    // attention (128 q-rows per block; bh on x for XCD L2 locality)
    flash_attn<<<dim3(64, 16), 256, 0, stream>>>(Qs, Kk, Vt, ctx);

    // output projection
    gemm_bt<EPI_PLAIN><<<dim3(64, 8), 256, 0, stream>>>(
        ctx, wo_t, b_o, nullptr, nullptr, attn, nullptr, nullptr, 8192, 1024, 1024);

    // h = LN(x + attn)  (f32 x residual, bf16 out, in-place over attn)
    ln_res<0><<<2048, 256, 0, stream>>>(x, attn, ln1g, ln1b, h);

    // FFN
    gemm_bt<EPI_RELU><<<dim3(64, 32), 256, 0, stream>>>(
        h, w1_t, b1, nullptr, nullptr, ffn1, nullptr, nullptr, 8192, 4096, 1024);
    gemm_bt<EPI_PLAIN><<<dim3(64, 8), 256, 0, stream>>>(
        ffn1, w2_t, b2, nullptr, nullptr, ffn2, nullptr, nullptr, 8192, 1024, 4096);

    // out = LN(h + ffn2) -> f32
    ln_res<1><<<2048, 256, 0, stream>>>(h, ffn2, ln2g, ln2b, out);

    (void)in_sizes; (void)n_in; (void)out_size; (void)ws_size;
}